// Round 1
// baseline (544.026 us; speedup 1.0000x reference)
//
#include <hip/hip_runtime.h>
#include <math.h>

#define B_ 8
#define C_ 64
#define H_ 128
#define W_ 128
#define O_ 64
#define HW_ (H_ * W_)

// ws layout: wt[576*64] floats ([c*9+k][o]) then wom[576*28] ([c*9+tap][j], j<18 offset, 18..26 mask)
__global__ void transpose_weights(const float* __restrict__ w_conv,
                                  const float* __restrict__ w_off,
                                  const float* __restrict__ w_msk,
                                  float* __restrict__ wt,
                                  float* __restrict__ wom)
{
    int tid = blockIdx.x * blockDim.x + threadIdx.x;  // 0..36863
    {
        int ck = tid >> 6, o = tid & 63;
        int c = ck / 9, k = ck % 9;
        wt[tid] = w_conv[(o * 64 + c) * 9 + k];
    }
    if (tid < 576 * 28) {
        int ct = tid / 28, j = tid % 28;
        int c = ct / 9, t = ct % 9;
        float v = 0.f;
        if (j < 18)      v = w_off[(j * 64 + c) * 9 + t];
        else if (j < 27) v = w_msk[((j - 18) * 64 + c) * 9 + t];
        wom[tid] = v;
    }
}

__global__ __launch_bounds__(256, 2) void deform_fused(
    const float* __restrict__ x,
    const float* __restrict__ wt,    // [c*9+k][64]
    const float* __restrict__ wom,   // [c*9+tap][28]
    float* __restrict__ out)
{
    int tid = blockIdx.x * blockDim.x + threadIdx.x;
    int w = tid & (W_ - 1);
    int h = (tid >> 7) & (H_ - 1);
    int b = tid >> 14;

    const float* xb = x + (size_t)b * C_ * HW_;

    // ---- phase 1: 27-channel 3x3 conv (18 offset + 9 mask pre-sigmoid) ----
    float off[18];
    float msk[9];
#pragma unroll
    for (int j = 0; j < 18; ++j) off[j] = 0.f;
#pragma unroll
    for (int j = 0; j < 9; ++j) msk[j] = 0.f;

    for (int c = 0; c < C_; ++c) {
        const float* xp = xb + c * HW_;
        const float* wrow = wom + c * 9 * 28;
#pragma unroll
        for (int ty = 0; ty < 3; ++ty) {
            int yy = h + ty - 1;
            bool yok = (unsigned)yy < (unsigned)H_;
#pragma unroll
            for (int tx = 0; tx < 3; ++tx) {
                int xx = w + tx - 1;
                bool ok = yok && ((unsigned)xx < (unsigned)W_);
                float xv = ok ? xp[yy * W_ + xx] : 0.f;
                const float4* wp = (const float4*)(wrow + (ty * 3 + tx) * 28);
#pragma unroll
                for (int q = 0; q < 7; ++q) {
                    float4 wv = wp[q];
#pragma unroll
                    for (int r = 0; r < 4; ++r) {
                        int j = q * 4 + r;
                        float wc = (r == 0) ? wv.x : (r == 1) ? wv.y : (r == 2) ? wv.z : wv.w;
                        if (j < 18)      off[j] += xv * wc;
                        else if (j < 27) msk[j - 18] += xv * wc;
                    }
                }
            }
        }
    }

    // ---- phase 2: deformable sampling + einsum ----
    float acc[O_];
#pragma unroll
    for (int o = 0; o < O_; ++o) acc[o] = 0.f;

#pragma unroll
    for (int k = 0; k < 9; ++k) {
        const int ki = k / 3, kj = k % 3;
        float mk = 1.f / (1.f + expf(-msk[k]));
        float py = (float)(h + ki - 1) + off[2 * k];
        float px = (float)(w + kj - 1) + off[2 * k + 1];
        float y0f = floorf(py), x0f = floorf(px);
        int y0 = (int)y0f, x0 = (int)x0f;
        int y1 = y0 + 1, x1 = x0 + 1;
        float wy1 = py - y0f, wy0 = 1.f - wy1;
        float wx1 = px - x0f, wx0 = 1.f - wx1;
        bool vy0 = ((unsigned)y0 < (unsigned)H_);
        bool vy1 = ((unsigned)y1 < (unsigned)H_);
        bool vx0 = ((unsigned)x0 < (unsigned)W_);
        bool vx1 = ((unsigned)x1 < (unsigned)W_);
        int y0c = min(max(y0, 0), H_ - 1), y1c = min(max(y1, 0), H_ - 1);
        int x0c = min(max(x0, 0), W_ - 1), x1c = min(max(x1, 0), W_ - 1);
        float w00 = wy0 * wx0 * ((vy0 && vx0) ? mk : 0.f);
        float w01 = wy0 * wx1 * ((vy0 && vx1) ? mk : 0.f);
        float w10 = wy1 * wx0 * ((vy1 && vx0) ? mk : 0.f);
        float w11 = wy1 * wx1 * ((vy1 && vx1) ? mk : 0.f);
        int i00 = y0c * W_ + x0c;
        int i01 = y0c * W_ + x1c;
        int i10 = y1c * W_ + x0c;
        int i11 = y1c * W_ + x1c;

        for (int c = 0; c < C_; ++c) {
            const float* xp = xb + c * HW_;
            float s = w00 * xp[i00] + w01 * xp[i01] + w10 * xp[i10] + w11 * xp[i11];
            const float4* wr = (const float4*)(wt + (c * 9 + k) * 64);
#pragma unroll
            for (int q = 0; q < 16; ++q) {
                float4 wv = wr[q];
                acc[q * 4 + 0] += s * wv.x;
                acc[q * 4 + 1] += s * wv.y;
                acc[q * 4 + 2] += s * wv.z;
                acc[q * 4 + 3] += s * wv.w;
            }
        }
    }

    // ---- store ----
    float* op = out + (size_t)b * O_ * HW_ + h * W_ + w;
#pragma unroll
    for (int o = 0; o < O_; ++o) op[(size_t)o * HW_] = acc[o];
}

extern "C" void kernel_launch(void* const* d_in, const int* in_sizes, int n_in,
                              void* d_out, int out_size, void* d_ws, size_t ws_size,
                              hipStream_t stream) {
    const float* x      = (const float*)d_in[0];
    const float* w_conv = (const float*)d_in[1];
    const float* w_off  = (const float*)d_in[2];
    const float* w_msk  = (const float*)d_in[3];
    float* out = (float*)d_out;
    float* wt  = (float*)d_ws;        // 36864 floats
    float* wom = wt + 576 * 64;       // 16128 floats

    transpose_weights<<<144, 256, 0, stream>>>(w_conv, w_off, w_msk, wt, wom);

    int total = B_ * H_ * W_;         // 131072
    deform_fused<<<total / 256, 256, 0, stream>>>(x, wt, wom, out);
}

// Round 2
// 477.182 us; speedup vs baseline: 1.1401x; 1.1401x over previous
//
#include <hip/hip_runtime.h>
#include <math.h>

#define B_ 8
#define C_ 64
#define H_ 128
#define W_ 128
#define O_ 64
#define HW_ (H_ * W_)
#define PXB 128      // pixels per block
#define FSTR 29      // LDS stride for 27-float conv partials (odd-ish, conflict-free)
#define RSTR 65      // LDS stride for 64-float acc reduction (conflict-free)

// ws layout: wt[576*64] floats ([c*9+k][o]) then wom[576*28] ([c*9+tap][j], j<18 offset, 18..26 mask)
__global__ void transpose_weights(const float* __restrict__ w_conv,
                                  const float* __restrict__ w_off,
                                  const float* __restrict__ w_msk,
                                  float* __restrict__ wt,
                                  float* __restrict__ wom)
{
    int tid = blockIdx.x * blockDim.x + threadIdx.x;  // 0..36863
    {
        int ck = tid >> 6, o = tid & 63;
        int c = ck / 9, k = ck % 9;
        wt[tid] = w_conv[(o * 64 + c) * 9 + k];
    }
    if (tid < 576 * 28) {
        int ct = tid / 28, j = tid % 28;
        int c = ct / 9, t = ct % 9;
        float v = 0.f;
        if (j < 18)      v = w_off[(j * 64 + c) * 9 + t];
        else if (j < 27) v = w_msk[((j - 18) * 64 + c) * 9 + t];
        wom[tid] = v;
    }
}

__global__ __launch_bounds__(256, 4) void deform_fused(
    const float* __restrict__ x,
    const float* __restrict__ wt,    // [c*9+k][64]
    const float* __restrict__ wom,   // [c*9+tap][28]
    float* __restrict__ out)
{
    __shared__ float lds[PXB * RSTR];   // 33280 B; reused: conv partials, then acc reduction

    const int t = threadIdx.x;
    const int pix = t & (PXB - 1);
    const int grp = t >> 7;             // wave-uniform: waves 0,1 -> grp0; waves 2,3 -> grp1
    const int gpix = blockIdx.x * PXB + pix;
    const int w = gpix & (W_ - 1);
    const int h = (gpix >> 7) & (H_ - 1);
    const int b = gpix >> 14;
    const float* xb = x + (size_t)b * C_ * HW_;
    const int c0 = grp * 32;

    // ---- phase 1: partial 27-channel 3x3 conv over this group's 32 input channels ----
    float om[27];
#pragma unroll
    for (int j = 0; j < 27; ++j) om[j] = 0.f;

    for (int cc = 0; cc < 32; ++cc) {
        const int c = c0 + cc;
        const float* xp = xb + c * HW_;
        const int wb = __builtin_amdgcn_readfirstlane(c * 9 * 28);
        const float* wrow = wom + wb;
#pragma unroll
        for (int ty = 0; ty < 3; ++ty) {
            const int yy = h + ty - 1;
            const bool yok = (unsigned)yy < (unsigned)H_;
#pragma unroll
            for (int tx = 0; tx < 3; ++tx) {
                const int xx = w + tx - 1;
                const bool ok = yok && ((unsigned)xx < (unsigned)W_);
                const float xv = ok ? xp[yy * W_ + xx] : 0.f;
                const float* wr = wrow + (ty * 3 + tx) * 28;
#pragma unroll
                for (int j = 0; j < 27; ++j) om[j] += xv * wr[j];
            }
        }
    }

    // ---- reduce conv partials across the two c-groups via LDS ----
    if (grp == 1) {
#pragma unroll
        for (int j = 0; j < 27; ++j) lds[pix * FSTR + j] = om[j];
    }
    __syncthreads();
    if (grp == 0) {
#pragma unroll
        for (int j = 0; j < 27; ++j) om[j] += lds[pix * FSTR + j];
#pragma unroll
        for (int j = 18; j < 27; ++j) om[j] = 1.f / (1.f + expf(-om[j]));
#pragma unroll
        for (int j = 0; j < 27; ++j) lds[pix * FSTR + j] = om[j];
    }
    __syncthreads();
    if (grp == 1) {
#pragma unroll
        for (int j = 0; j < 27; ++j) om[j] = lds[pix * FSTR + j];
    }
    __syncthreads();   // all conv-partial reads done; lds free for acc reduction

    // ---- phase 2: deformable sampling + partial einsum over this group's 32 channels ----
    float acc[O_];
#pragma unroll
    for (int o = 0; o < O_; ++o) acc[o] = 0.f;

#pragma unroll
    for (int k = 0; k < 9; ++k) {
        const int ki = k / 3, kj = k % 3;
        const float mk = om[18 + k];
        const float py = (float)(h + ki - 1) + om[2 * k];
        const float px = (float)(w + kj - 1) + om[2 * k + 1];
        const float y0f = floorf(py), x0f = floorf(px);
        const int y0i = (int)y0f, x0i = (int)x0f;
        const int y1i = y0i + 1, x1i = x0i + 1;
        const float wy1 = py - y0f, wy0 = 1.f - wy1;
        const float wx1 = px - x0f, wx0 = 1.f - wx1;
        const bool vy0 = ((unsigned)y0i < (unsigned)H_);
        const bool vy1 = ((unsigned)y1i < (unsigned)H_);
        const bool vx0 = ((unsigned)x0i < (unsigned)W_);
        const bool vx1 = ((unsigned)x1i < (unsigned)W_);
        const int y0c = min(max(y0i, 0), H_ - 1), y1c = min(max(y1i, 0), H_ - 1);
        const int x0c = min(max(x0i, 0), W_ - 1), x1c = min(max(x1i, 0), W_ - 1);
        const float w00 = wy0 * wx0 * ((vy0 && vx0) ? mk : 0.f);
        const float w01 = wy0 * wx1 * ((vy0 && vx1) ? mk : 0.f);
        const float w10 = wy1 * wx0 * ((vy1 && vx0) ? mk : 0.f);
        const float w11 = wy1 * wx1 * ((vy1 && vx1) ? mk : 0.f);
        const int i00 = y0c * W_ + x0c;
        const int i01 = y0c * W_ + x1c;
        const int i10 = y1c * W_ + x0c;
        const int i11 = y1c * W_ + x1c;

        for (int cc = 0; cc < 32; ++cc) {
            const int c = c0 + cc;
            const float* xp = xb + c * HW_;
            const float s = w00 * xp[i00] + w01 * xp[i01] + w10 * xp[i10] + w11 * xp[i11];
            const int wb2 = __builtin_amdgcn_readfirstlane((c * 9 + k) * 64);
            const float4* wr = (const float4*)(wt + wb2);
#pragma unroll
            for (int q = 0; q < 16; ++q) {
                const float4 wv = wr[q];
                acc[q * 4 + 0] += s * wv.x;
                acc[q * 4 + 1] += s * wv.y;
                acc[q * 4 + 2] += s * wv.z;
                acc[q * 4 + 3] += s * wv.w;
            }
        }
    }

    // ---- reduce acc across the two c-groups, store ----
    if (grp == 1) {
#pragma unroll
        for (int o = 0; o < O_; ++o) lds[pix * RSTR + o] = acc[o];
    }
    __syncthreads();
    if (grp == 0) {
        float* op = out + (size_t)b * O_ * HW_ + h * W_ + w;
#pragma unroll
        for (int o = 0; o < O_; ++o) op[(size_t)o * HW_] = acc[o] + lds[pix * RSTR + o];
    }
}

extern "C" void kernel_launch(void* const* d_in, const int* in_sizes, int n_in,
                              void* d_out, int out_size, void* d_ws, size_t ws_size,
                              hipStream_t stream) {
    const float* x      = (const float*)d_in[0];
    const float* w_conv = (const float*)d_in[1];
    const float* w_off  = (const float*)d_in[2];
    const float* w_msk  = (const float*)d_in[3];
    float* out = (float*)d_out;
    float* wt  = (float*)d_ws;        // 36864 floats
    float* wom = wt + 576 * 64;       // 16128 floats

    transpose_weights<<<144, 256, 0, stream>>>(w_conv, w_off, w_msk, wt, wom);

    int total = B_ * H_ * W_;         // 131072 pixels
    deform_fused<<<total / PXB, 256, 0, stream>>>(x, wt, wom, out);
}